// Round 1
// baseline (253.728 us; speedup 1.0000x reference)
//
#include <hip/hip_runtime.h>

#define NCOMP   100000
#define D_CA    12
#define D_COURT 4
#define D_CATE  4
#define D_TOT   20
#define NCAUSE  200
#define NCOURT  50
#define NRES    10

// ---------------- kernel 1: per-company start offsets (binary search) ----------
__global__ void seg_starts_kernel(const int* __restrict__ seg, int n_events,
                                  int* __restrict__ start) {
    int c = blockIdx.x * blockDim.x + threadIdx.x;
    if (c > NCOMP) return;
    if (c == NCOMP) { start[c] = n_events; return; }
    int lo = 0, hi = n_events;
    while (lo < hi) {
        int mid = (lo + hi) >> 1;
        if (seg[mid] < c) lo = mid + 1; else hi = mid;
    }
    start[c] = lo;
}

// ---------------- kernel 2: wave-per-company fused gather+decay+reduce+proj ----
__global__ __launch_bounds__(256)
void company_emb_kernel(const int* __restrict__ cause_idx,
                        const int* __restrict__ court_idx,
                        const int* __restrict__ cate_idx,
                        const float* __restrict__ time_interval,
                        const float* __restrict__ ca_table,
                        const float* __restrict__ court_table,
                        const float* __restrict__ cate_table,
                        const float* __restrict__ proj_w,
                        const float* __restrict__ decay_w,
                        const int* __restrict__ start,
                        float* __restrict__ out) {
    __shared__ __align__(16) float lds_ca[NCAUSE * D_CA];      // 2400
    __shared__ __align__(16) float lds_court[NCOURT * D_COURT]; // 200
    __shared__ __align__(16) float lds_cate[NRES * D_CATE];     // 40
    __shared__ __align__(16) float lds_w[D_TOT * D_TOT];        // 400

    for (int i = threadIdx.x; i < NCAUSE * D_CA; i += 256) lds_ca[i] = ca_table[i];
    for (int i = threadIdx.x; i < NCOURT * D_COURT; i += 256) lds_court[i] = court_table[i];
    for (int i = threadIdx.x; i < NRES * D_CATE; i += 256) lds_cate[i] = cate_table[i];
    for (int i = threadIdx.x; i < D_TOT * D_TOT; i += 256) lds_w[i] = proj_w[i];
    __syncthreads();

    const float dw = decay_w[0];
    const int lane = threadIdx.x & 63;
    const int wid = (blockIdx.x * blockDim.x + threadIdx.x) >> 6;
    const int total_waves = (gridDim.x * blockDim.x) >> 6;

    for (int c = wid; c < NCOMP; c += total_waves) {
        const int s0 = start[c];
        const int s1 = start[c + 1];

        float acc[D_TOT];
#pragma unroll
        for (int d = 0; d < D_TOT; ++d) acc[d] = 0.0f;

        for (int i = s0 + lane; i < s1; i += 64) {
            const int ca = cause_idx[i];
            const int co = court_idx[i];
            const int ct = cate_idx[i];
            const float t = time_interval[i];
            // decay = decay_w / ln(e + t)
            const float decay = dw / logf(2.718281828459045f + t);

            const float4* car = (const float4*)(lds_ca + ca * D_CA);
            const float4 a0 = car[0];
            const float4 a1 = car[1];
            const float4 a2 = car[2];
            const float4 b0 = *(const float4*)(lds_court + co * D_COURT);
            const float4 c0 = *(const float4*)(lds_cate + ct * D_CATE);

            acc[0]  += decay * a0.x;  acc[1]  += decay * a0.y;
            acc[2]  += decay * a0.z;  acc[3]  += decay * a0.w;
            acc[4]  += decay * a1.x;  acc[5]  += decay * a1.y;
            acc[6]  += decay * a1.z;  acc[7]  += decay * a1.w;
            acc[8]  += decay * a2.x;  acc[9]  += decay * a2.y;
            acc[10] += decay * a2.z;  acc[11] += decay * a2.w;
            acc[12] += decay * b0.x;  acc[13] += decay * b0.y;
            acc[14] += decay * b0.z;  acc[15] += decay * b0.w;
            acc[16] += decay * c0.x;  acc[17] += decay * c0.y;
            acc[18] += decay * c0.z;  acc[19] += decay * c0.w;
        }

        // butterfly reduce each of the 20 dims across the 64-lane wave
#pragma unroll
        for (int d = 0; d < D_TOT; ++d) {
            float v = acc[d];
            v += __shfl_xor(v, 1);
            v += __shfl_xor(v, 2);
            v += __shfl_xor(v, 4);
            v += __shfl_xor(v, 8);
            v += __shfl_xor(v, 16);
            v += __shfl_xor(v, 32);
            acc[d] = v;
        }

        // fused projection: out[c][o] = sum_d S[d] * W[o][d], lane o < 20
        if (lane < D_TOT) {
            float o = 0.0f;
#pragma unroll
            for (int d = 0; d < D_TOT; ++d) o += acc[d] * lds_w[lane * D_TOT + d];
            out[c * D_TOT + lane] = o;
        }
    }
}

extern "C" void kernel_launch(void* const* d_in, const int* in_sizes, int n_in,
                              void* d_out, int out_size, void* d_ws, size_t ws_size,
                              hipStream_t stream) {
    const int* cause_idx = (const int*)d_in[0];
    const int* court_idx = (const int*)d_in[1];
    const int* cate_idx  = (const int*)d_in[2];
    const int* seg_ids   = (const int*)d_in[3];
    const float* time_interval = (const float*)d_in[4];
    const float* ca_table      = (const float*)d_in[5];
    const float* court_table   = (const float*)d_in[6];
    const float* cate_table    = (const float*)d_in[7];
    const float* proj_w        = (const float*)d_in[8];
    const float* decay_w       = (const float*)d_in[9];
    float* out = (float*)d_out;
    const int n_events = in_sizes[0];

    int* start = (int*)d_ws;  // (NCOMP + 1) ints = 400,004 B

    {
        const int n = NCOMP + 1;
        seg_starts_kernel<<<(n + 255) / 256, 256, 0, stream>>>(seg_ids, n_events, start);
    }
    {
        const int blocks = 2048;  // 8192 waves, grid-stride over 100K companies
        company_emb_kernel<<<blocks, 256, 0, stream>>>(
            cause_idx, court_idx, cate_idx, time_interval,
            ca_table, court_table, cate_table, proj_w, decay_w,
            start, out);
    }
}

// Round 2
// 156.262 us; speedup vs baseline: 1.6237x; 1.6237x over previous
//
#include <hip/hip_runtime.h>

#define NCOMP   100000
#define D_CA    12
#define D_COURT 4
#define D_CATE  4
#define D_TOT   20
#define NCAUSE  200
#define NCOURT  50
#define NRES    10
#define LPC     4      // lanes per company

// ---------------- kernel 1: event-parallel segment boundary detection ----------
__global__ void seg_starts_kernel(const int* __restrict__ seg, int n_events,
                                  int* __restrict__ start) {
    int i = blockIdx.x * blockDim.x + threadIdx.x;
    if (i >= n_events) return;
    const int cur = seg[i];
    const int prev = (i == 0) ? -1 : seg[i - 1];
    // start[c] = first event index with seg >= c
    for (int c = prev + 1; c <= cur; ++c) start[c] = i;
    if (i == n_events - 1) {
        for (int c = cur + 1; c <= NCOMP; ++c) start[c] = n_events;
    }
}

// ---------------- kernel 2: 4-lane-group per company ---------------------------
__global__ __launch_bounds__(256)
void company_emb_kernel(const int* __restrict__ cause_idx,
                        const int* __restrict__ court_idx,
                        const int* __restrict__ cate_idx,
                        const float* __restrict__ time_interval,
                        const float* __restrict__ ca_table,
                        const float* __restrict__ court_table,
                        const float* __restrict__ cate_table,
                        const float* __restrict__ proj_w,
                        const float* __restrict__ decay_w,
                        const int* __restrict__ start,
                        float* __restrict__ out) {
    __shared__ __align__(16) float lds_ca[NCAUSE * D_CA];       // 2400
    __shared__ __align__(16) float lds_court[NCOURT * D_COURT]; // 200
    __shared__ __align__(16) float lds_cate[NRES * D_CATE];     // 40
    __shared__ __align__(16) float lds_w[D_TOT * D_TOT];        // 400

    for (int i = threadIdx.x; i < NCAUSE * D_CA; i += 256) lds_ca[i] = ca_table[i];
    for (int i = threadIdx.x; i < NCOURT * D_COURT; i += 256) lds_court[i] = court_table[i];
    for (int i = threadIdx.x; i < NRES * D_CATE; i += 256) lds_cate[i] = cate_table[i];
    for (int i = threadIdx.x; i < D_TOT * D_TOT; i += 256) lds_w[i] = proj_w[i];
    __syncthreads();

    const float dw = decay_w[0];
    const int tid = blockIdx.x * 256 + threadIdx.x;
    const int c = tid >> 2;               // company id (one per 4-lane group)
    const int sub = threadIdx.x & (LPC - 1);
    if (c >= NCOMP) return;               // after barrier: safe

    const int s0 = start[c];
    const int s1 = start[c + 1];

    float acc[D_TOT];
#pragma unroll
    for (int d = 0; d < D_TOT; ++d) acc[d] = 0.0f;

    for (int i = s0 + sub; i < s1; i += LPC) {
        const int ca = cause_idx[i];
        const int co = court_idx[i];
        const int ct = cate_idx[i];
        const float t = time_interval[i];
        const float decay = __fdividef(dw, __logf(2.718281828459045f + t));

        const float4* car = (const float4*)(lds_ca + ca * D_CA);
        const float4 a0 = car[0];
        const float4 a1 = car[1];
        const float4 a2 = car[2];
        const float4 b0 = *(const float4*)(lds_court + co * D_COURT);
        const float4 c0 = *(const float4*)(lds_cate + ct * D_CATE);

        acc[0]  += decay * a0.x;  acc[1]  += decay * a0.y;
        acc[2]  += decay * a0.z;  acc[3]  += decay * a0.w;
        acc[4]  += decay * a1.x;  acc[5]  += decay * a1.y;
        acc[6]  += decay * a1.z;  acc[7]  += decay * a1.w;
        acc[8]  += decay * a2.x;  acc[9]  += decay * a2.y;
        acc[10] += decay * a2.z;  acc[11] += decay * a2.w;
        acc[12] += decay * b0.x;  acc[13] += decay * b0.y;
        acc[14] += decay * b0.z;  acc[15] += decay * b0.w;
        acc[16] += decay * c0.x;  acc[17] += decay * c0.y;
        acc[18] += decay * c0.z;  acc[19] += decay * c0.w;
    }

    // reduce across the 4-lane group (xor 1, 2 stay inside aligned quads)
#pragma unroll
    for (int d = 0; d < D_TOT; ++d) {
        float v = acc[d];
        v += __shfl_xor(v, 1);
        v += __shfl_xor(v, 2);
        acc[d] = v;
    }

    // fused projection: each lane computes 5 of the 20 outputs
#pragma unroll
    for (int k = 0; k < 5; ++k) {
        const int o = sub * 5 + k;
        float s = 0.0f;
#pragma unroll
        for (int d = 0; d < D_TOT; ++d) s += acc[d] * lds_w[o * D_TOT + d];
        out[c * D_TOT + o] = s;
    }
}

extern "C" void kernel_launch(void* const* d_in, const int* in_sizes, int n_in,
                              void* d_out, int out_size, void* d_ws, size_t ws_size,
                              hipStream_t stream) {
    const int* cause_idx = (const int*)d_in[0];
    const int* court_idx = (const int*)d_in[1];
    const int* cate_idx  = (const int*)d_in[2];
    const int* seg_ids   = (const int*)d_in[3];
    const float* time_interval = (const float*)d_in[4];
    const float* ca_table      = (const float*)d_in[5];
    const float* court_table   = (const float*)d_in[6];
    const float* cate_table    = (const float*)d_in[7];
    const float* proj_w        = (const float*)d_in[8];
    const float* decay_w       = (const float*)d_in[9];
    float* out = (float*)d_out;
    const int n_events = in_sizes[0];

    int* start = (int*)d_ws;  // (NCOMP + 1) ints

    {
        const int blocks = (n_events + 255) / 256;
        seg_starts_kernel<<<blocks, 256, 0, stream>>>(seg_ids, n_events, start);
    }
    {
        const int groups = NCOMP;                       // one 4-lane group per company
        const int blocks = (groups * LPC + 255) / 256;  // 1563
        company_emb_kernel<<<blocks, 256, 0, stream>>>(
            cause_idx, court_idx, cate_idx, time_interval,
            ca_table, court_table, cate_table, proj_w, decay_w,
            start, out);
    }
}

// Round 4
// 148.894 us; speedup vs baseline: 1.7041x; 1.0495x over previous
//
#include <hip/hip_runtime.h>

#define NCOMP   100000
#define D_CA    12
#define D_COURT 4
#define D_CATE  4
#define D_TOT   20
#define NCAUSE  200
#define NCOURT  50
#define NRES    10
#define LPC     8              // lanes per company
#define CPB     32             // companies per block (256/LPC)

// ---- one fused kernel: in-block binary search + gather/decay/reduce/proj ----
__global__ __launch_bounds__(256)
void fused_company_kernel(const int* __restrict__ cause_idx,
                          const int* __restrict__ court_idx,
                          const int* __restrict__ cate_idx,
                          const int* __restrict__ seg_ids,
                          const float* __restrict__ time_interval,
                          const float* __restrict__ ca_table,
                          const float* __restrict__ court_table,
                          const float* __restrict__ cate_table,
                          const float* __restrict__ proj_w,
                          const float* __restrict__ decay_w,
                          int n_events,
                          float* __restrict__ out) {
    __shared__ __align__(16) float lds_ca[NCAUSE * D_CA];       // 2400 f
    __shared__ __align__(16) float lds_court[NCOURT * D_COURT]; // 200 f
    __shared__ __align__(16) float lds_cate[NRES * D_CATE];     // 40 f
    __shared__ __align__(16) float lds_w[D_TOT * D_TOT];        // 400 f
    __shared__ int lds_start[CPB + 1];

    for (int i = threadIdx.x; i < NCAUSE * D_CA; i += 256) lds_ca[i] = ca_table[i];
    for (int i = threadIdx.x; i < NCOURT * D_COURT; i += 256) lds_court[i] = court_table[i];
    for (int i = threadIdx.x; i < NRES * D_CATE; i += 256) lds_cate[i] = cate_table[i];
    for (int i = threadIdx.x; i < D_TOT * D_TOT; i += 256) lds_w[i] = proj_w[i];

    // 33 threads binary-search the block's company boundaries.
    // Top ~10 levels touch the same addresses in every block -> L1/L2 hot.
    if (threadIdx.x <= CPB) {
        const int c = blockIdx.x * CPB + threadIdx.x;
        int lo = 0, hi = n_events;
        while (lo < hi) {
            const int mid = (lo + hi) >> 1;
            if (seg_ids[mid] < c) lo = mid + 1; else hi = mid;
        }
        lds_start[threadIdx.x] = lo;
    }
    __syncthreads();

    const float dw = decay_w[0];
    const int g   = threadIdx.x >> 3;        // group within block: 0..31
    const int sub = threadIdx.x & (LPC - 1); // lane within group: 0..7
    const int c   = blockIdx.x * CPB + g;
    const int s0  = lds_start[g];
    const int s1  = lds_start[g + 1];

    float acc[D_TOT];
#pragma unroll
    for (int d = 0; d < D_TOT; ++d) acc[d] = 0.0f;

#define EV_BODY(I)                                                           \
    {                                                                        \
        const int   ca = cause_idx[I];                                       \
        const int   co = court_idx[I];                                       \
        const int   ct = cate_idx[I];                                        \
        const float t  = time_interval[I];                                   \
        const float dec = __fdividef(dw, __logf(2.718281828459045f + t));    \
        const float4* car = (const float4*)(lds_ca + ca * D_CA);             \
        const float4 a0 = car[0];                                            \
        const float4 a1 = car[1];                                            \
        const float4 a2 = car[2];                                            \
        const float4 b0 = *(const float4*)(lds_court + co * D_COURT);        \
        const float4 c0 = *(const float4*)(lds_cate + ct * D_CATE);          \
        acc[0]  += dec * a0.x;  acc[1]  += dec * a0.y;                       \
        acc[2]  += dec * a0.z;  acc[3]  += dec * a0.w;                       \
        acc[4]  += dec * a1.x;  acc[5]  += dec * a1.y;                       \
        acc[6]  += dec * a1.z;  acc[7]  += dec * a1.w;                       \
        acc[8]  += dec * a2.x;  acc[9]  += dec * a2.y;                       \
        acc[10] += dec * a2.z;  acc[11] += dec * a2.w;                       \
        acc[12] += dec * b0.x;  acc[13] += dec * b0.y;                       \
        acc[14] += dec * b0.z;  acc[15] += dec * b0.w;                       \
        acc[16] += dec * c0.x;  acc[17] += dec * c0.y;                       \
        acc[18] += dec * c0.z;  acc[19] += dec * c0.w;                       \
    }

    int i = s0 + sub;
    // 2-deep manual unroll: 8 independent global loads in flight per lane
    for (; i + LPC < s1; i += 2 * LPC) {
        EV_BODY(i);
        EV_BODY(i + LPC);
    }
    if (i < s1) EV_BODY(i);
#undef EV_BODY

    // reduce across the 8-lane group (xor 1,2,4 stay within the group)
#pragma unroll
    for (int d = 0; d < D_TOT; ++d) {
        float v = acc[d];
        v += __shfl_xor(v, 1);
        v += __shfl_xor(v, 2);
        v += __shfl_xor(v, 4);
        acc[d] = v;
    }

    // fused projection: lane sub covers outputs {sub, sub+8, sub+16} ∩ [0,20)
    for (int o = sub; o < D_TOT; o += LPC) {
        float s = 0.0f;
#pragma unroll
        for (int d = 0; d < D_TOT; ++d) s += acc[d] * lds_w[o * D_TOT + d];
        out[c * D_TOT + o] = s;
    }
}

extern "C" void kernel_launch(void* const* d_in, const int* in_sizes, int n_in,
                              void* d_out, int out_size, void* d_ws, size_t ws_size,
                              hipStream_t stream) {
    const int* cause_idx = (const int*)d_in[0];
    const int* court_idx = (const int*)d_in[1];
    const int* cate_idx  = (const int*)d_in[2];
    const int* seg_ids   = (const int*)d_in[3];
    const float* time_interval = (const float*)d_in[4];
    const float* ca_table      = (const float*)d_in[5];
    const float* court_table   = (const float*)d_in[6];
    const float* cate_table    = (const float*)d_in[7];
    const float* proj_w        = (const float*)d_in[8];
    const float* decay_w       = (const float*)d_in[9];
    float* out = (float*)d_out;
    const int n_events = in_sizes[0];

    const int blocks = NCOMP / CPB;  // 3125
    fused_company_kernel<<<blocks, 256, 0, stream>>>(
        cause_idx, court_idx, cate_idx, seg_ids, time_interval,
        ca_table, court_table, cate_table, proj_w, decay_w,
        n_events, out);
}